// Round 10
// baseline (102.581 us; speedup 1.0000x reference)
//
#include <hip/hip_runtime.h>
#include <hip/hip_bf16.h>
#include <string.h>

#define ND 512   // directions
#define NP 64    // points per ray
#define NR 32    // rank
#define NF 256   // virtual subcarriers
#define RS 40    // ushorts per LDS row (80 B): 16B-aligned rows, 2-way banks only

typedef __attribute__((ext_vector_type(8))) short bf16x8;   // 8 bf16 = 4 VGPRs
typedef __attribute__((ext_vector_type(4))) float f32x4;
typedef __attribute__((ext_vector_type(4))) unsigned int uint4v;

// packed 2x f32 -> bf16 (RNE) — lowers to v_cvt_pk_bf16_f32 on gfx950
__device__ inline unsigned pk(float x, float y) {
    __hip_bfloat162 h = __float22bfloat162_rn(make_float2(x, y));
    unsigned u;
    memcpy(&u, &h, sizeof(u));   // no-op register move; bit_cast rejects this type
    return u;
}
__device__ inline uint2 pk4(float4 x) {
    return make_uint2(pk(x.x, x.y), pk(x.z, x.w));
}
__device__ inline bf16x8 cvt8(float4 a, float4 b) {
    uint4v u = {pk(a.x, a.y), pk(a.z, a.w), pk(b.x, b.y), pk(b.z, b.w)};
    return __builtin_bit_cast(bf16x8, u);
}
// scalar f32 -> bf16 (RNE)
__device__ inline unsigned short f2bf(float x) {
    unsigned u = __builtin_bit_cast(unsigned, x);
    u += 0x7FFFu + ((u >> 16) & 1u);
    return (unsigned short)(u >> 16);
}
// negate 8 packed bf16 (sign-bit XOR)
__device__ inline bf16x8 neg8(bf16x8 v) {
    uint4v u = __builtin_bit_cast(uint4v, v);
    u ^= (uint4v){0x80008000u, 0x80008000u, 0x80008000u, 0x80008000u};
    return __builtin_bit_cast(bf16x8, u);
}

// Monolithic: one block per direction d; 4 waves; wave wv owns p-strip
// 16wv..16wv+15 and loops all 16 n-tiles. Chained-MFMA conj pattern
// (verified R3-R8):
//   re = mfma(x_i, vi, mfma(x_r, vr, 0)),  im = mfma(x_i, -vr, mfma(x_r, vi, 0))
// cum LDS planes store dt*cum_re and -dt*cum_im (p=0 row zeroed -> the
// second-order term's p>=1 restriction is automatic).
__global__ __launch_bounds__(256, 4) void lrrt_mono_kernel(
    const float* __restrict__ att_re, const float* __restrict__ att_im,
    const float* __restrict__ rad_re, const float* __restrict__ rad_im,
    const float* __restrict__ freq_re, const float* __restrict__ freq_im,
    const int* __restrict__ mrl, float* __restrict__ out)
{
    __shared__ __align__(16) unsigned short s_a[6][NP * RS];  // 30720 B
    __shared__ float s_tot[256];                              // 1 KB
    __shared__ float s_red[4][NF][2];                         // 8 KB

    const int t = threadIdx.x;
    const int d = blockIdx.x;
    const size_t base = (size_t)d * (NP * NR);
    const int lane = t & 63, wv = t >> 6, kg = lane >> 4, m_lo = lane & 15;
    const float dt = (float)(*mrl) / (float)NP;

    // --- A. stage att/rad bf16 into padded LDS (coalesced float4 + cvt_pk) ---
#pragma unroll
    for (int half = 0; half < 2; ++half) {
        const int w = t + half * 256;        // float4 index 0..511
        const int p = w >> 3;
        const int c = (w & 7) * 4;
        const size_t g = base + (size_t)p * NR + c;
        const int lo = p * RS + c;
        *(uint2*)&s_a[0][lo] = pk4(*(const float4*)(att_re + g));
        *(uint2*)&s_a[1][lo] = pk4(*(const float4*)(att_im + g));
        *(uint2*)&s_a[2][lo] = pk4(*(const float4*)(rad_re + g));
        *(uint2*)&s_a[3][lo] = pk4(*(const float4*)(rad_im + g));
    }

    // --- A'. segmented fp32 cumsum of att along p (overlaps staging) ---
    const int cs_r = t & 31, cs_reim = (t >> 5) & 1, cs_seg = t >> 6;
    float vals[16];
    {
        const float* src = cs_reim ? att_im : att_re;
        float run = 0.f;
#pragma unroll
        for (int i = 0; i < 16; ++i) {
            run += src[base + (size_t)(cs_seg * 16 + i) * NR + cs_r];
            vals[i] = run;
        }
        s_tot[t] = run;
    }
    __syncthreads();

    // --- B. add segment offsets; store dt*cum_re / -dt*cum_im; zero p=0 ---
    {
        float off = 0.f;
#pragma unroll
        for (int s = 0; s < 3; ++s)
            if (s < cs_seg) off += s_tot[s * 64 + cs_reim * 32 + cs_r];
        const float sc = cs_reim ? -dt : dt;
        unsigned short* dst = s_a[4 + cs_reim];
#pragma unroll
        for (int i = 0; i < 16; ++i) {
            const int p = cs_seg * 16 + i;
            dst[p * RS + cs_r] = (p == 0) ? (unsigned short)0
                                          : f2bf(sc * (vals[i] + off));
        }
    }
    __syncthreads();

    // --- C. A fragments for this wave's p-strip (b128, 2-way banks = free) ---
    const int aoff = (wv * 16 + m_lo) * RS + 8 * kg;
    const bf16x8 a_r = *(const bf16x8*)&s_a[0][aoff];
    const bf16x8 a_i = *(const bf16x8*)&s_a[1][aoff];
    const bf16x8 r_r = *(const bf16x8*)&s_a[2][aoff];
    const bf16x8 r_i = *(const bf16x8*)&s_a[3][aoff];
    const bf16x8 c_r = *(const bf16x8*)&s_a[4][aoff];
    const bf16x8 c_i = *(const bf16x8*)&s_a[5][aoff];

    const f32x4 zero = {0.f, 0.f, 0.f, 0.f};

    // --- D. q-loop over 16 n-tiles with manual B prefetch rotation ---
    const size_t boff0 = (size_t)m_lo * NR + 8 * kg;   // q = 0
    float4 br0 = *(const float4*)(freq_re + boff0);
    float4 br1 = *(const float4*)(freq_re + boff0 + 4);
    float4 bi0 = *(const float4*)(freq_im + boff0);
    float4 bi1 = *(const float4*)(freq_im + boff0 + 4);

#pragma unroll 1
    for (int q = 0; q < 16; ++q) {
        const bf16x8 vr = cvt8(br0, br1);
        const bf16x8 vi = cvt8(bi0, bi1);
        if (q < 15) {   // issue next tile's loads before the MFMA/combine
            const size_t bo = (size_t)(16 * (q + 1) + m_lo) * NR + 8 * kg;
            br0 = *(const float4*)(freq_re + bo);
            br1 = *(const float4*)(freq_re + bo + 4);
            bi0 = *(const float4*)(freq_im + bo);
            bi1 = *(const float4*)(freq_im + bo + 4);
        }
        const bf16x8 vn = neg8(vr);

        f32x4 Are = __builtin_amdgcn_mfma_f32_16x16x32_bf16(a_r, vr, zero, 0, 0, 0);
        f32x4 Aim = __builtin_amdgcn_mfma_f32_16x16x32_bf16(a_r, vi, zero, 0, 0, 0);
        f32x4 Bre = __builtin_amdgcn_mfma_f32_16x16x32_bf16(r_r, vr, zero, 0, 0, 0);
        f32x4 Bim = __builtin_amdgcn_mfma_f32_16x16x32_bf16(r_r, vi, zero, 0, 0, 0);
        f32x4 Ure = __builtin_amdgcn_mfma_f32_16x16x32_bf16(c_r, vr, zero, 0, 0, 0);
        f32x4 Uim = __builtin_amdgcn_mfma_f32_16x16x32_bf16(c_r, vi, zero, 0, 0, 0);
        Are = __builtin_amdgcn_mfma_f32_16x16x32_bf16(a_i, vi, Are, 0, 0, 0);
        Aim = __builtin_amdgcn_mfma_f32_16x16x32_bf16(a_i, vn, Aim, 0, 0, 0);
        Bre = __builtin_amdgcn_mfma_f32_16x16x32_bf16(r_i, vi, Bre, 0, 0, 0);
        Bim = __builtin_amdgcn_mfma_f32_16x16x32_bf16(r_i, vn, Bim, 0, 0, 0);
        Ure = __builtin_amdgcn_mfma_f32_16x16x32_bf16(c_i, vi, Ure, 0, 0, 0);
        Uim = __builtin_amdgcn_mfma_f32_16x16x32_bf16(c_i, vn, Uim, 0, 0, 0);

        float sr = 0.f, si = 0.f;
#pragma unroll
        for (int i = 0; i < 4; ++i) {
            const float qre = Bre[i] * Are[i] - Bim[i] * Aim[i];
            const float qim = Bre[i] * Aim[i] + Bim[i] * Are[i];
            const float cre = 1.0f + Ure[i];   // dt folded into cum planes
            const float cim = Uim[i];
            sr = fmaf(qre, cre, fmaf(-qim, cim, sr));
            si = fmaf(qim, cre, fmaf(qre, cim, si));
        }
        // reduce over the 4 row-groups (p within the wave's strip)
        sr += __shfl_xor(sr, 16, 64); si += __shfl_xor(si, 16, 64);
        sr += __shfl_xor(sr, 32, 64); si += __shfl_xor(si, 32, 64);
        if (lane < 16) {
            s_red[wv][16 * q + lane][0] = sr;
            s_red[wv][16 * q + lane][1] = si;
        }
    }
    __syncthreads();

    // --- E. cross-wave sum; rotated atomics (de-convoy same-address RMW) ---
    const float scale = dt / (float)ND;
#pragma unroll
    for (int j = 0; j < 2; ++j) {
        const int o = ((t + 256 * j) + 2 * d) & 511;   // out index, rotated by d
        const int f = o & 255, comp = o >> 8;
        const float v = s_red[0][f][comp] + s_red[1][f][comp]
                      + s_red[2][f][comp] + s_red[3][f][comp];
        atomicAdd(&out[o], v * scale);   // out[comp*NF + f] == out[o]
    }
}

extern "C" void kernel_launch(void* const* d_in, const int* in_sizes, int n_in,
                              void* d_out, int out_size, void* d_ws, size_t ws_size,
                              hipStream_t stream) {
    const float* att_re = (const float*)d_in[0];
    const float* att_im = (const float*)d_in[1];
    const float* rad_re = (const float*)d_in[2];
    const float* rad_im = (const float*)d_in[3];
    const float* freq_re = (const float*)d_in[4];
    const float* freq_im = (const float*)d_in[5];
    const int* mrl = (const int*)d_in[6];
    float* out = (float*)d_out;

    // d_out is poisoned 0xAA before every launch; we accumulate with atomics.
    (void)hipMemsetAsync(d_out, 0, (size_t)out_size * sizeof(float), stream);

    lrrt_mono_kernel<<<ND, 256, 0, stream>>>(
        att_re, att_im, rad_re, rad_im, freq_re, freq_im, mrl, out);
}